// Round 2
// baseline (751.367 us; speedup 1.0000x reference)
//
#include <hip/hip_runtime.h>
#include <math.h>

#define BATCH   4
#define SEQLEN  4096
#define DMODEL  256
#define DINNER  1024
#define NHEADS  16
#define HEADDIM 64
#define DSTATE  64
#define CONVDIM 1152
#define DPROJ   2192
#define NCHUNK  64
#define CHUNK   64
#define ROWS    (BATCH*SEQLEN)   // 16384

typedef unsigned short u16;

// bf16 <-> f32 helpers (storage-only precision loss, RNE rounding)
static __device__ __forceinline__ float bf2f(u16 u) {
    return __uint_as_float(((unsigned int)u) << 16);
}
static __device__ __forceinline__ float bflo(unsigned int p) {
    return __uint_as_float(p << 16);
}
static __device__ __forceinline__ float bfhi(unsigned int p) {
    return __uint_as_float(p & 0xffff0000u);
}
static __device__ __forceinline__ u16 f2bf(float f) {
    unsigned int x = __float_as_uint(f);
    x += 0x7fffu + ((x >> 16) & 1u);
    return (u16)(x >> 16);
}

// ---------------------------------------------------------------------------
// GEMM: C[M][N] = A[M][KTOT] @ Bw[N][KTOT]^T  (row-major, B transposed)
// 64x64 tile, 256 threads, 4x4 register blocking, K-tile 32.
// A: fp32 or bf16; Bw: fp32; C: fp32 or bf16.
// ---------------------------------------------------------------------------
template<int KTOT, bool A_BF, bool C_BF>
__global__ __launch_bounds__(256) void gemm_abt(const void* __restrict__ Ap,
                                                const float* __restrict__ Bw,
                                                void* __restrict__ Cp,
                                                int M, int N)
{
    __shared__ float As[32][68];
    __shared__ float Bs[32][68];

    const int m0 = blockIdx.y * 64;
    const int n0 = blockIdx.x * 64;
    const int tid = threadIdx.x;
    const int ty = tid >> 4;
    const int tx = tid & 15;

    float acc[4][4] = {};

    const int r  = tid >> 2;        // 0..63
    const int kq = (tid & 3) * 8;   // 0,8,16,24

    for (int kt = 0; kt < KTOT; kt += 32) {
        // A tile (64 x 32) -> As[k][m]
        if constexpr (A_BF) {
            const u16* ap = (const u16*)Ap + (size_t)(m0 + r) * KTOT + kt + kq;
            uint4 av = *(const uint4*)ap;   // 8 bf16
            As[kq+0][r] = bflo(av.x); As[kq+1][r] = bfhi(av.x);
            As[kq+2][r] = bflo(av.y); As[kq+3][r] = bfhi(av.y);
            As[kq+4][r] = bflo(av.z); As[kq+5][r] = bfhi(av.z);
            As[kq+6][r] = bflo(av.w); As[kq+7][r] = bfhi(av.w);
        } else {
            const float* ap = (const float*)Ap + (size_t)(m0 + r) * KTOT + kt + kq;
            float4 a0 = *(const float4*)ap;
            float4 a1 = *(const float4*)(ap + 4);
            As[kq+0][r] = a0.x; As[kq+1][r] = a0.y; As[kq+2][r] = a0.z; As[kq+3][r] = a0.w;
            As[kq+4][r] = a1.x; As[kq+5][r] = a1.y; As[kq+6][r] = a1.z; As[kq+7][r] = a1.w;
        }
        // B tile (64 x 32) with N guard
        {
            const int n = n0 + r;
            float4 b0 = make_float4(0.f,0.f,0.f,0.f);
            float4 b1 = make_float4(0.f,0.f,0.f,0.f);
            if (n < N) {
                const float* bp = Bw + (size_t)n * KTOT + kt + kq;
                b0 = *(const float4*)bp;
                b1 = *(const float4*)(bp + 4);
            }
            Bs[kq+0][r] = b0.x; Bs[kq+1][r] = b0.y; Bs[kq+2][r] = b0.z; Bs[kq+3][r] = b0.w;
            Bs[kq+4][r] = b1.x; Bs[kq+5][r] = b1.y; Bs[kq+6][r] = b1.z; Bs[kq+7][r] = b1.w;
        }
        __syncthreads();
        #pragma unroll
        for (int k = 0; k < 32; ++k) {
            float4 av = *(const float4*)&As[k][ty*4];
            float4 bv = *(const float4*)&Bs[k][tx*4];
            acc[0][0] += av.x*bv.x; acc[0][1] += av.x*bv.y; acc[0][2] += av.x*bv.z; acc[0][3] += av.x*bv.w;
            acc[1][0] += av.y*bv.x; acc[1][1] += av.y*bv.y; acc[1][2] += av.y*bv.z; acc[1][3] += av.y*bv.w;
            acc[2][0] += av.z*bv.x; acc[2][1] += av.z*bv.y; acc[2][2] += av.z*bv.z; acc[2][3] += av.z*bv.w;
            acc[3][0] += av.w*bv.x; acc[3][1] += av.w*bv.y; acc[3][2] += av.w*bv.z; acc[3][3] += av.w*bv.w;
        }
        __syncthreads();
    }

    #pragma unroll
    for (int ii = 0; ii < 4; ++ii) {
        const int m = m0 + ty*4 + ii;
        const int n = n0 + tx*4;
        if (n < N) {   // N is a multiple of 4; a 4-group never straddles
            if constexpr (C_BF) {
                ushort4 o;
                o.x = f2bf(acc[ii][0]); o.y = f2bf(acc[ii][1]);
                o.z = f2bf(acc[ii][2]); o.w = f2bf(acc[ii][3]);
                *(ushort4*)((u16*)Cp + (size_t)m * N + n) = o;
            } else {
                float4 o = make_float4(acc[ii][0], acc[ii][1], acc[ii][2], acc[ii][3]);
                *(float4*)((float*)Cp + (size_t)m * N + n) = o;
            }
        }
    }
}

// ---------------------------------------------------------------------------
// Depthwise causal conv (W=4) + bias + SiLU over xBC channels of zxbcdt
// ---------------------------------------------------------------------------
__global__ __launch_bounds__(256) void conv_kernel(const u16* __restrict__ zxbcdt,
                                                   const float* __restrict__ conv_w,
                                                   const float* __restrict__ conv_b,
                                                   u16* __restrict__ xconv)
{
    const int idx = blockIdx.x * 256 + threadIdx.x;   // over ROWS*CONVDIM
    const int ch  = idx % CONVDIM;
    const int row = idx / CONVDIM;
    const int l   = row & (SEQLEN-1);
    const int b   = row >> 12;

    float acc = conv_b[ch];
    #pragma unroll
    for (int w = 0; w < 4; ++w) {
        const int ls = l - 3 + w;
        if (ls >= 0) {
            acc += bf2f(zxbcdt[(size_t)(b*SEQLEN + ls) * DPROJ + DINNER + ch]) * conv_w[ch*4 + w];
        }
    }
    xconv[idx] = f2bf(acc / (1.f + __expf(-acc)));   // SiLU
}

// ---------------------------------------------------------------------------
// dt = softplus(raw + dt_bias);  dA = -exp(A_log) * dt
// ---------------------------------------------------------------------------
__global__ __launch_bounds__(256) void dt_kernel(const u16* __restrict__ zxbcdt,
                                                 const float* __restrict__ dt_bias,
                                                 const float* __restrict__ A_log,
                                                 float* __restrict__ dt,
                                                 float* __restrict__ dA)
{
    const int idx = blockIdx.x * 256 + threadIdx.x;  // over ROWS*NHEADS
    const int h = idx & (NHEADS-1);
    const int row = idx >> 4;
    const float x = bf2f(zxbcdt[(size_t)row * DPROJ + (DPROJ - NHEADS) + h]) + dt_bias[h];
    const float sp = (x > 20.f) ? x : log1pf(__expf(x));
    dt[idx] = sp;
    dA[idx] = -__expf(A_log[h]) * sp;
}

// ---------------------------------------------------------------------------
// SSD phase A: per (b, chunk, head):
//   Y_diag = (C B^T .* L) @ (x*dt) -> ybuf ;  S_c = B_scaled^T @ (x*dt) -> states
// ---------------------------------------------------------------------------
__global__ __launch_bounds__(256) void ssd_phaseA(const u16* __restrict__ xconv,
                                                  const float* __restrict__ dtb,
                                                  const float* __restrict__ dAb,
                                                  u16* __restrict__ ybuf,
                                                  u16* __restrict__ states,
                                                  float* __restrict__ acs_g,
                                                  float* __restrict__ asum_g)
{
    const int h = blockIdx.x, c = blockIdx.y, b = blockIdx.z;
    const int tid = threadIdx.x;
    const int l0 = c * CHUNK;

    __shared__ float xdt[64][65];
    __shared__ float Bt[64][65];
    __shared__ float CtM[64][65];   // C tile, reused for masked/decayed M
    __shared__ float a_cs[64];

    if (tid < 64) a_cs[tid] = dAb[(size_t)(b*SEQLEN + l0 + tid) * NHEADS + h];
    __syncthreads();
    if (tid == 0) {
        float s = 0.f;
        for (int i = 0; i < 64; ++i) { s += a_cs[i]; a_cs[i] = s; }
    }
    __syncthreads();
    const float a_last = a_cs[63];

    for (int it = 0; it < 16; ++it) {
        const int row = it*4 + (tid >> 6);
        const int col = tid & 63;
        const u16* rp = xconv + (size_t)(b*SEQLEN + l0 + row) * CONVDIM;
        const float dtv = dtb[(size_t)(b*SEQLEN + l0 + row) * NHEADS + h];
        xdt[row][col] = bf2f(rp[h*HEADDIM + col]) * dtv;
        Bt[row][col]  = bf2f(rp[DINNER + col]);
        CtM[row][col] = bf2f(rp[DINNER + DSTATE + col]);
    }
    __syncthreads();

    const int ty = tid >> 4, tx = tid & 15;
    const int i0 = ty*4, j0 = tx*4;

    // G = C @ B^T
    float accG[4][4] = {};
    for (int n = 0; n < 64; ++n) {
        float cv[4], bv[4];
        #pragma unroll
        for (int ii = 0; ii < 4; ++ii) cv[ii] = CtM[i0+ii][n];
        #pragma unroll
        for (int jj = 0; jj < 4; ++jj) bv[jj] = Bt[j0+jj][n];
        #pragma unroll
        for (int ii = 0; ii < 4; ++ii)
            #pragma unroll
            for (int jj = 0; jj < 4; ++jj) accG[ii][jj] += cv[ii]*bv[jj];
    }
    __syncthreads();

    // overwrite CtM with masked+decayed M; scale Bt rows by chunk-end decay
    #pragma unroll
    for (int ii = 0; ii < 4; ++ii)
        #pragma unroll
        for (int jj = 0; jj < 4; ++jj) {
            const int i = i0+ii, j = j0+jj;
            CtM[i][j] = (j <= i) ? accG[ii][jj] * __expf(a_cs[i] - a_cs[j]) : 0.f;
        }
    for (int it = 0; it < 16; ++it) {
        const int row = it*4 + (tid >> 6);
        const int col = tid & 63;
        Bt[row][col] *= __expf(a_last - a_cs[row]);
    }
    __syncthreads();

    // Y_diag = M @ xdt
    {
        float acc[4][4] = {};
        for (int j = 0; j < 64; ++j) {
            float mv[4], xv[4];
            #pragma unroll
            for (int ii = 0; ii < 4; ++ii) mv[ii] = CtM[i0+ii][j];
            #pragma unroll
            for (int pp = 0; pp < 4; ++pp) xv[pp] = xdt[j][j0+pp];
            #pragma unroll
            for (int ii = 0; ii < 4; ++ii)
                #pragma unroll
                for (int pp = 0; pp < 4; ++pp) acc[ii][pp] += mv[ii]*xv[pp];
        }
        #pragma unroll
        for (int ii = 0; ii < 4; ++ii) {
            const int i = i0+ii;
            ushort4 o;
            o.x = f2bf(acc[ii][0]); o.y = f2bf(acc[ii][1]);
            o.z = f2bf(acc[ii][2]); o.w = f2bf(acc[ii][3]);
            *(ushort4*)(ybuf + (size_t)(b*SEQLEN + l0 + i) * DINNER + h*HEADDIM + j0) = o;
        }
    }

    // S_c[n][p] = sum_j Bt_scaled[j][n] * xdt[j][p]
    {
        float acc[4][4] = {};
        for (int j = 0; j < 64; ++j) {
            float bv[4], xv[4];
            #pragma unroll
            for (int nn = 0; nn < 4; ++nn) bv[nn] = Bt[j][i0+nn];
            #pragma unroll
            for (int pp = 0; pp < 4; ++pp) xv[pp] = xdt[j][j0+pp];
            #pragma unroll
            for (int nn = 0; nn < 4; ++nn)
                #pragma unroll
                for (int pp = 0; pp < 4; ++pp) acc[nn][pp] += bv[nn]*xv[pp];
        }
        #pragma unroll
        for (int nn = 0; nn < 4; ++nn) {
            ushort4 o;
            o.x = f2bf(acc[nn][0]); o.y = f2bf(acc[nn][1]);
            o.z = f2bf(acc[nn][2]); o.w = f2bf(acc[nn][3]);
            *(ushort4*)(states + ((((size_t)b*NCHUNK + c)*NHEADS + h)*DSTATE + (i0+nn))*HEADDIM + j0) = o;
        }
    }

    if (tid < 64) acs_g[(((size_t)b*NCHUNK + c)*NHEADS + h)*CHUNK + tid] = a_cs[tid];
    if (tid == 0) asum_g[((size_t)b*NHEADS + h)*NCHUNK + c] = a_last;
}

// ---------------------------------------------------------------------------
// Inter-chunk scan, in place: states[c] <- P_c ; P_{c+1} = exp(asum_c)*P_c + S_c
// ---------------------------------------------------------------------------
__global__ __launch_bounds__(256) void ssd_scan(u16* __restrict__ states,
                                                const float* __restrict__ asum_g)
{
    const int gid = blockIdx.x;
    const int s = gid & 15;
    const int h = (gid >> 4) & (NHEADS-1);
    const int b = gid >> 8;
    const int elem = s*256 + threadIdx.x;   // n*64+p

    const float* as = asum_g + ((size_t)b*NHEADS + h)*NCHUNK;
    float P = 0.f;
    for (int c = 0; c < NCHUNK; ++c) {
        const size_t idx = (((size_t)b*NCHUNK + c)*NHEADS + h)*4096 + elem;
        const float sv = bf2f(states[idx]);
        states[idx] = f2bf(P);
        P = P * __expf(as[c]) + sv;
    }
}

// ---------------------------------------------------------------------------
// SSD phase C: Y = Y_diag + exp(a_cs)*(C @ S_prev) + x*D ; then y *= silu(z)
// ---------------------------------------------------------------------------
__global__ __launch_bounds__(256) void ssd_phaseC(const u16* __restrict__ xconv,
                                                  const u16* __restrict__ zxbcdt,
                                                  const u16* __restrict__ states,
                                                  const float* __restrict__ acs_g,
                                                  const float* __restrict__ Dvec,
                                                  u16* __restrict__ ybuf)
{
    const int h = blockIdx.x, c = blockIdx.y, b = blockIdx.z;
    const int tid = threadIdx.x;
    const int l0 = c * CHUNK;

    __shared__ float Ct[64][65];
    __shared__ float Sp[64][65];
    __shared__ float a_cs[64];

    if (tid < 64) a_cs[tid] = acs_g[(((size_t)b*NCHUNK + c)*NHEADS + h)*CHUNK + tid];
    for (int it = 0; it < 16; ++it) {
        const int row = it*4 + (tid >> 6);
        const int col = tid & 63;
        Ct[row][col] = bf2f(xconv[(size_t)(b*SEQLEN + l0 + row) * CONVDIM + DINNER + DSTATE + col]);
        Sp[row][col] = bf2f(states[((((size_t)b*NCHUNK + c)*NHEADS + h)*DSTATE + row)*HEADDIM + col]);
    }
    __syncthreads();

    const float Dh = Dvec[h];
    const int ty = tid >> 4, tx = tid & 15;
    const int i0 = ty*4, p0 = tx*4;

    float acc[4][4] = {};
    for (int n = 0; n < 64; ++n) {
        float cv[4], sv[4];
        #pragma unroll
        for (int ii = 0; ii < 4; ++ii) cv[ii] = Ct[i0+ii][n];
        #pragma unroll
        for (int pp = 0; pp < 4; ++pp) sv[pp] = Sp[n][p0+pp];
        #pragma unroll
        for (int ii = 0; ii < 4; ++ii)
            #pragma unroll
            for (int pp = 0; pp < 4; ++pp) acc[ii][pp] += cv[ii]*sv[pp];
    }

    #pragma unroll
    for (int ii = 0; ii < 4; ++ii) {
        const int i = i0+ii;
        const int l = l0 + i;
        const float e = __expf(a_cs[i]);
        const u16* xr = xconv  + (size_t)(b*SEQLEN + l) * CONVDIM + h*HEADDIM + p0;
        const u16* zr = zxbcdt + (size_t)(b*SEQLEN + l) * DPROJ   + h*HEADDIM + p0;
        u16* yp = ybuf + (size_t)(b*SEQLEN + l) * DINNER + h*HEADDIM + p0;
        ushort4 yv4 = *(const ushort4*)yp;
        ushort4 xv4 = *(const ushort4*)xr;
        ushort4 zv4 = *(const ushort4*)zr;
        float yv[4] = {bf2f(yv4.x), bf2f(yv4.y), bf2f(yv4.z), bf2f(yv4.w)};
        float xv[4] = {bf2f(xv4.x), bf2f(xv4.y), bf2f(xv4.z), bf2f(xv4.w)};
        float zv[4] = {bf2f(zv4.x), bf2f(zv4.y), bf2f(zv4.z), bf2f(zv4.w)};
        ushort4 o;
        u16* op = (u16*)&o;
        #pragma unroll
        for (int pp = 0; pp < 4; ++pp) {
            const float y = yv[pp] + e*acc[ii][pp] + xv[pp]*Dh;
            const float sz = zv[pp] / (1.f + __expf(-zv[pp]));
            op[pp] = f2bf(y * sz);
        }
        *(ushort4*)yp = o;
    }
}

// ---------------------------------------------------------------------------
// RMSNorm over 1024, in place (bf16)
// ---------------------------------------------------------------------------
__global__ __launch_bounds__(256) void rmsnorm_kernel(u16* __restrict__ y,
                                                      const float* __restrict__ w)
{
    __shared__ float red[4];
    const int row = blockIdx.x;
    const int tid = threadIdx.x;
    ushort4* yp = (ushort4*)(y + (size_t)row * DINNER);
    ushort4 v = yp[tid];
    float f0 = bf2f(v.x), f1 = bf2f(v.y), f2 = bf2f(v.z), f3 = bf2f(v.w);
    float ss = f0*f0 + f1*f1 + f2*f2 + f3*f3;
    #pragma unroll
    for (int o = 32; o > 0; o >>= 1) ss += __shfl_down(ss, o);
    if ((tid & 63) == 0) red[tid >> 6] = ss;
    __syncthreads();
    const float total = red[0] + red[1] + red[2] + red[3];
    const float scale = rsqrtf(total * (1.f/1024.f) + 1e-5f);
    const float4 wv = ((const float4*)w)[tid];
    ushort4 o;
    o.x = f2bf(f0 * scale * wv.x);
    o.y = f2bf(f1 * scale * wv.y);
    o.z = f2bf(f2 * scale * wv.z);
    o.w = f2bf(f3 * scale * wv.w);
    yp[tid] = o;
}

// ---------------------------------------------------------------------------
extern "C" void kernel_launch(void* const* d_in, const int* in_sizes, int n_in,
                              void* d_out, int out_size, void* d_ws, size_t ws_size,
                              hipStream_t stream)
{
    const float* u          = (const float*)d_in[0];
    const float* in_proj_w  = (const float*)d_in[1];
    const float* conv_w     = (const float*)d_in[2];
    const float* conv_b     = (const float*)d_in[3];
    const float* dt_bias    = (const float*)d_in[4];
    const float* A_log      = (const float*)d_in[5];
    const float* Dvec       = (const float*)d_in[6];
    const float* norm_w     = (const float*)d_in[7];
    const float* out_proj_w = (const float*)d_in[8];
    float* out = (float*)d_out;

    // workspace layout (total ~172 MiB): fp32 small buffers first, then bf16
    float* dtb  = (float*)d_ws;                         // ROWS*NHEADS
    float* dAb  = dtb  + (size_t)ROWS*NHEADS;           // ROWS*NHEADS
    float* acs  = dAb  + (size_t)ROWS*NHEADS;           // B*NC*H*CHUNK
    float* asum = acs  + (size_t)BATCH*NCHUNK*NHEADS*CHUNK;  // B*H*NC
    u16* zxbcdt = (u16*)(asum + (size_t)BATCH*NHEADS*NCHUNK);
    u16* xconv  = zxbcdt + (size_t)ROWS*DPROJ;
    u16* ybuf   = xconv  + (size_t)ROWS*CONVDIM;
    u16* states = ybuf   + (size_t)ROWS*DINNER;         // B*NC*H*64*64

    gemm_abt<DMODEL, false, true><<<dim3((DPROJ+63)/64, ROWS/64), 256, 0, stream>>>(u, in_proj_w, zxbcdt, ROWS, DPROJ);
    conv_kernel<<<(ROWS*CONVDIM)/256, 256, 0, stream>>>(zxbcdt, conv_w, conv_b, xconv);
    dt_kernel<<<(ROWS*NHEADS)/256, 256, 0, stream>>>(zxbcdt, dt_bias, A_log, dtb, dAb);
    ssd_phaseA<<<dim3(NHEADS, NCHUNK, BATCH), 256, 0, stream>>>(xconv, dtb, dAb, ybuf, states, acs, asum);
    ssd_scan<<<BATCH*NHEADS*16, 256, 0, stream>>>(states, asum);
    ssd_phaseC<<<dim3(NHEADS, NCHUNK, BATCH), 256, 0, stream>>>(xconv, zxbcdt, states, acs, Dvec, ybuf);
    rmsnorm_kernel<<<ROWS, 256, 0, stream>>>(ybuf, norm_w);
    gemm_abt<DINNER, true, false><<<dim3(DMODEL/64, ROWS/64), 256, 0, stream>>>(ybuf, out_proj_w, out, ROWS, DMODEL);
}

// Round 4
// 534.407 us; speedup vs baseline: 1.4060x; 1.4060x over previous
//
#include <hip/hip_runtime.h>
#include <math.h>

#define BATCH   4
#define SEQLEN  4096
#define DMODEL  256
#define DINNER  1024
#define NHEADS  16
#define HEADDIM 64
#define DSTATE  64
#define CONVDIM 1152
#define DPROJ   2192
#define NCHUNK  64
#define CHUNK   64
#define ROWS    (BATCH*SEQLEN)   // 16384
#define NPAD1   2304             // DPROJ padded to multiple of 128

typedef unsigned short u16;
using frag  = __attribute__((ext_vector_type(8))) short;   // 8 bf16 (4 VGPRs)
using f32x4 = __attribute__((ext_vector_type(4))) float;

// bf16 <-> f32 helpers (storage-only precision loss, RNE rounding)
static __device__ __forceinline__ float bf2f(u16 u) {
    return __uint_as_float(((unsigned int)u) << 16);
}
static __device__ __forceinline__ u16 f2bf(float f) {
    unsigned int x = __float_as_uint(f);
    x += 0x7fffu + ((x >> 16) & 1u);
    return (u16)(x >> 16);
}

// ---------------------------------------------------------------------------
// fp32 -> bf16 convert (4 elems/thread). Rows >= valid_rows write zeros
// (used to zero-pad in_proj_w to NPAD1 rows).
// ---------------------------------------------------------------------------
__global__ __launch_bounds__(256) void cvt_bf16(const float* __restrict__ in,
                                                u16* __restrict__ out,
                                                int total4, int valid_rows, int colshift)
{
    const int i = blockIdx.x * 256 + threadIdx.x;
    if (i >= total4) return;
    const int e = i * 4;
    const int row = e >> colshift;
    ushort4 o;
    if (row < valid_rows) {
        float4 v = *(const float4*)(in + e);
        o.x = f2bf(v.x); o.y = f2bf(v.y); o.z = f2bf(v.z); o.w = f2bf(v.w);
    } else {
        o.x = 0; o.y = 0; o.z = 0; o.w = 0;
    }
    *(ushort4*)(out + e) = o;
}

// ---------------------------------------------------------------------------
// bf16 MFMA GEMM: C[M][N] = A[M][KTOT] @ W[N][KTOT]^T
// A: [M][KTOT] bf16 row-major.  W: [>=gridDim.x*128][KTOT] bf16 row-major.
// 128x128 tile, BK=64, 256 threads = 4 waves (2x2 of 64x64 each).
// Reg-staged 2-phase loop; next K-tile global loads issued before MFMA block.
// C store guarded by col < N (stride N).
// ---------------------------------------------------------------------------
template<int KTOT, bool C_BF>
__global__ __launch_bounds__(256) void gemm_mfma(const u16* __restrict__ A,
                                                 const u16* __restrict__ W,
                                                 void* __restrict__ Cp,
                                                 int N)
{
    __shared__ u16 As[128*64];
    __shared__ u16 Ws[128*64];

    const int m0 = blockIdx.y * 128;
    const int n0 = blockIdx.x * 128;
    const int tid = threadIdx.x;
    const int lane = tid & 63;
    const int w  = tid >> 6;
    const int wr = w >> 1, wc = w & 1;

    // staging: thread covers rows {it*32+tid/8}, 8 bf16 at col (tid&7)*8
    const int srow = tid >> 3;          // 0..31
    const int scol = (tid & 7) * 8;     // 0..56

    const int lrow = lane & 15;
    const int kgrp = lane >> 4;         // 0..3

    f32x4 acc[4][4] = {};

    uint4 ra[4], rw[4];
    #pragma unroll
    for (int it = 0; it < 4; ++it) {
        const int r = it*32 + srow;
        ra[it] = *(const uint4*)(A + (size_t)(m0 + r)*KTOT + scol);
        rw[it] = *(const uint4*)(W + (size_t)(n0 + r)*KTOT + scol);
    }

    for (int kt = 0; kt < KTOT; kt += 64) {
        __syncthreads();   // previous compute done before overwriting LDS
        #pragma unroll
        for (int it = 0; it < 4; ++it) {
            const int r = it*32 + srow;
            *(uint4*)&As[r*64 + scol] = ra[it];
            *(uint4*)&Ws[r*64 + scol] = rw[it];
        }
        __syncthreads();
        if (kt + 64 < KTOT) {   // prefetch next K-tile; latency hides under MFMA
            #pragma unroll
            for (int it = 0; it < 4; ++it) {
                const int r = it*32 + srow;
                ra[it] = *(const uint4*)(A + (size_t)(m0 + r)*KTOT + kt + 64 + scol);
                rw[it] = *(const uint4*)(W + (size_t)(n0 + r)*KTOT + kt + 64 + scol);
            }
        }
        #pragma unroll
        for (int ks = 0; ks < 2; ++ks) {
            frag af[4], bf[4];
            #pragma unroll
            for (int i = 0; i < 4; ++i)
                af[i] = *(const frag*)&As[(wr*64 + i*16 + lrow)*64 + ks*32 + kgrp*8];
            #pragma unroll
            for (int j = 0; j < 4; ++j)
                bf[j] = *(const frag*)&Ws[(wc*64 + j*16 + lrow)*64 + ks*32 + kgrp*8];
            #pragma unroll
            for (int i = 0; i < 4; ++i)
                #pragma unroll
                for (int j = 0; j < 4; ++j)
                    acc[i][j] = __builtin_amdgcn_mfma_f32_16x16x32_bf16(af[i], bf[j], acc[i][j], 0, 0, 0);
        }
    }

    // C/D layout: col = lane&15, row = (lane>>4)*4 + reg
    #pragma unroll
    for (int i = 0; i < 4; ++i) {
        #pragma unroll
        for (int j = 0; j < 4; ++j) {
            const int col = n0 + wc*64 + j*16 + lrow;
            if (col < N) {
                #pragma unroll
                for (int r = 0; r < 4; ++r) {
                    const int row = m0 + wr*64 + i*16 + kgrp*4 + r;
                    if constexpr (C_BF)
                        ((u16*)Cp)[(size_t)row * N + col] = f2bf(acc[i][j][r]);
                    else
                        ((float*)Cp)[(size_t)row * N + col] = acc[i][j][r];
                }
            }
        }
    }
}

// ---------------------------------------------------------------------------
// Depthwise causal conv (W=4) + bias + SiLU over xBC channels of zxbcdt
// ---------------------------------------------------------------------------
__global__ __launch_bounds__(256) void conv_kernel(const u16* __restrict__ zxbcdt,
                                                   const float* __restrict__ conv_w,
                                                   const float* __restrict__ conv_b,
                                                   u16* __restrict__ xconv)
{
    const int idx = blockIdx.x * 256 + threadIdx.x;   // over ROWS*CONVDIM
    const int ch  = idx % CONVDIM;
    const int row = idx / CONVDIM;
    const int l   = row & (SEQLEN-1);
    const int b   = row >> 12;

    float acc = conv_b[ch];
    #pragma unroll
    for (int w = 0; w < 4; ++w) {
        const int ls = l - 3 + w;
        if (ls >= 0) {
            acc += bf2f(zxbcdt[(size_t)(b*SEQLEN + ls) * DPROJ + DINNER + ch]) * conv_w[ch*4 + w];
        }
    }
    xconv[idx] = f2bf(acc / (1.f + __expf(-acc)));   // SiLU
}

// ---------------------------------------------------------------------------
// dt = softplus(raw + dt_bias);  dA = -exp(A_log) * dt
// ---------------------------------------------------------------------------
__global__ __launch_bounds__(256) void dt_kernel(const u16* __restrict__ zxbcdt,
                                                 const float* __restrict__ dt_bias,
                                                 const float* __restrict__ A_log,
                                                 float* __restrict__ dt,
                                                 float* __restrict__ dA)
{
    const int idx = blockIdx.x * 256 + threadIdx.x;  // over ROWS*NHEADS
    const int h = idx & (NHEADS-1);
    const int row = idx >> 4;
    const float x = bf2f(zxbcdt[(size_t)row * DPROJ + (DPROJ - NHEADS) + h]) + dt_bias[h];
    const float sp = (x > 20.f) ? x : log1pf(__expf(x));
    dt[idx] = sp;
    dA[idx] = -__expf(A_log[h]) * sp;
}

// ---------------------------------------------------------------------------
// SSD phase A: per (b, chunk, head):
//   Y_diag = (C B^T .* L) @ (x*dt) -> ybuf ;  S_c = B_scaled^T @ (x*dt) -> states
// ---------------------------------------------------------------------------
__global__ __launch_bounds__(256) void ssd_phaseA(const u16* __restrict__ xconv,
                                                  const float* __restrict__ dtb,
                                                  const float* __restrict__ dAb,
                                                  u16* __restrict__ ybuf,
                                                  u16* __restrict__ states,
                                                  float* __restrict__ acs_g,
                                                  float* __restrict__ asum_g)
{
    const int h = blockIdx.x, c = blockIdx.y, b = blockIdx.z;
    const int tid = threadIdx.x;
    const int l0 = c * CHUNK;

    __shared__ float xdt[64][65];
    __shared__ float Bt[64][65];
    __shared__ float CtM[64][65];   // C tile, reused for masked/decayed M
    __shared__ float a_cs[64];

    if (tid < 64) a_cs[tid] = dAb[(size_t)(b*SEQLEN + l0 + tid) * NHEADS + h];
    __syncthreads();
    if (tid == 0) {
        float s = 0.f;
        for (int i = 0; i < 64; ++i) { s += a_cs[i]; a_cs[i] = s; }
    }
    __syncthreads();
    const float a_last = a_cs[63];

    for (int it = 0; it < 16; ++it) {
        const int row = it*4 + (tid >> 6);
        const int col = tid & 63;
        const u16* rp = xconv + (size_t)(b*SEQLEN + l0 + row) * CONVDIM;
        const float dtv = dtb[(size_t)(b*SEQLEN + l0 + row) * NHEADS + h];
        xdt[row][col] = bf2f(rp[h*HEADDIM + col]) * dtv;
        Bt[row][col]  = bf2f(rp[DINNER + col]);
        CtM[row][col] = bf2f(rp[DINNER + DSTATE + col]);
    }
    __syncthreads();

    const int ty = tid >> 4, tx = tid & 15;
    const int i0 = ty*4, j0 = tx*4;

    // G = C @ B^T
    float accG[4][4] = {};
    for (int n = 0; n < 64; ++n) {
        float cv[4], bv[4];
        #pragma unroll
        for (int ii = 0; ii < 4; ++ii) cv[ii] = CtM[i0+ii][n];
        #pragma unroll
        for (int jj = 0; jj < 4; ++jj) bv[jj] = Bt[j0+jj][n];
        #pragma unroll
        for (int ii = 0; ii < 4; ++ii)
            #pragma unroll
            for (int jj = 0; jj < 4; ++jj) accG[ii][jj] += cv[ii]*bv[jj];
    }
    __syncthreads();

    // overwrite CtM with masked+decayed M; scale Bt rows by chunk-end decay
    #pragma unroll
    for (int ii = 0; ii < 4; ++ii)
        #pragma unroll
        for (int jj = 0; jj < 4; ++jj) {
            const int i = i0+ii, j = j0+jj;
            CtM[i][j] = (j <= i) ? accG[ii][jj] * __expf(a_cs[i] - a_cs[j]) : 0.f;
        }
    for (int it = 0; it < 16; ++it) {
        const int row = it*4 + (tid >> 6);
        const int col = tid & 63;
        Bt[row][col] *= __expf(a_last - a_cs[row]);
    }
    __syncthreads();

    // Y_diag = M @ xdt
    {
        float acc[4][4] = {};
        for (int j = 0; j < 64; ++j) {
            float mv[4], xv[4];
            #pragma unroll
            for (int ii = 0; ii < 4; ++ii) mv[ii] = CtM[i0+ii][j];
            #pragma unroll
            for (int pp = 0; pp < 4; ++pp) xv[pp] = xdt[j][j0+pp];
            #pragma unroll
            for (int ii = 0; ii < 4; ++ii)
                #pragma unroll
                for (int pp = 0; pp < 4; ++pp) acc[ii][pp] += mv[ii]*xv[pp];
        }
        #pragma unroll
        for (int ii = 0; ii < 4; ++ii) {
            const int i = i0+ii;
            ushort4 o;
            o.x = f2bf(acc[ii][0]); o.y = f2bf(acc[ii][1]);
            o.z = f2bf(acc[ii][2]); o.w = f2bf(acc[ii][3]);
            *(ushort4*)(ybuf + (size_t)(b*SEQLEN + l0 + i) * DINNER + h*HEADDIM + j0) = o;
        }
    }

    // S_c[n][p] = sum_j Bt_scaled[j][n] * xdt[j][p]
    {
        float acc[4][4] = {};
        for (int j = 0; j < 64; ++j) {
            float bv[4], xv[4];
            #pragma unroll
            for (int nn = 0; nn < 4; ++nn) bv[nn] = Bt[j][i0+nn];
            #pragma unroll
            for (int pp = 0; pp < 4; ++pp) xv[pp] = xdt[j][j0+pp];
            #pragma unroll
            for (int nn = 0; nn < 4; ++nn)
                #pragma unroll
                for (int pp = 0; pp < 4; ++pp) acc[nn][pp] += bv[nn]*xv[pp];
        }
        #pragma unroll
        for (int nn = 0; nn < 4; ++nn) {
            ushort4 o;
            o.x = f2bf(acc[nn][0]); o.y = f2bf(acc[nn][1]);
            o.z = f2bf(acc[nn][2]); o.w = f2bf(acc[nn][3]);
            *(ushort4*)(states + ((((size_t)b*NCHUNK + c)*NHEADS + h)*DSTATE + (i0+nn))*HEADDIM + j0) = o;
        }
    }

    if (tid < 64) acs_g[(((size_t)b*NCHUNK + c)*NHEADS + h)*CHUNK + tid] = a_cs[tid];
    if (tid == 0) asum_g[((size_t)b*NHEADS + h)*NCHUNK + c] = a_last;
}

// ---------------------------------------------------------------------------
// Inter-chunk scan, in place: states[c] <- P_c ; P_{c+1} = exp(asum_c)*P_c + S_c
// ---------------------------------------------------------------------------
__global__ __launch_bounds__(256) void ssd_scan(u16* __restrict__ states,
                                                const float* __restrict__ asum_g)
{
    const int gid = blockIdx.x;
    const int s = gid & 15;
    const int h = (gid >> 4) & (NHEADS-1);
    const int b = gid >> 8;
    const int elem = s*256 + threadIdx.x;   // n*64+p

    const float* as = asum_g + ((size_t)b*NHEADS + h)*NCHUNK;
    float P = 0.f;
    for (int c = 0; c < NCHUNK; ++c) {
        const size_t idx = (((size_t)b*NCHUNK + c)*NHEADS + h)*4096 + elem;
        const float sv = bf2f(states[idx]);
        states[idx] = f2bf(P);
        P = P * __expf(as[c]) + sv;
    }
}

// ---------------------------------------------------------------------------
// SSD phase C: Y = Y_diag + exp(a_cs)*(C @ S_prev) + x*D ; then y *= silu(z)
// ---------------------------------------------------------------------------
__global__ __launch_bounds__(256) void ssd_phaseC(const u16* __restrict__ xconv,
                                                  const u16* __restrict__ zxbcdt,
                                                  const u16* __restrict__ states,
                                                  const float* __restrict__ acs_g,
                                                  const float* __restrict__ Dvec,
                                                  u16* __restrict__ ybuf)
{
    const int h = blockIdx.x, c = blockIdx.y, b = blockIdx.z;
    const int tid = threadIdx.x;
    const int l0 = c * CHUNK;

    __shared__ float Ct[64][65];
    __shared__ float Sp[64][65];
    __shared__ float a_cs[64];

    if (tid < 64) a_cs[tid] = acs_g[(((size_t)b*NCHUNK + c)*NHEADS + h)*CHUNK + tid];
    for (int it = 0; it < 16; ++it) {
        const int row = it*4 + (tid >> 6);
        const int col = tid & 63;
        Ct[row][col] = bf2f(xconv[(size_t)(b*SEQLEN + l0 + row) * CONVDIM + DINNER + DSTATE + col]);
        Sp[row][col] = bf2f(states[((((size_t)b*NCHUNK + c)*NHEADS + h)*DSTATE + row)*HEADDIM + col]);
    }
    __syncthreads();

    const float Dh = Dvec[h];
    const int ty = tid >> 4, tx = tid & 15;
    const int i0 = ty*4, p0 = tx*4;

    float acc[4][4] = {};
    for (int n = 0; n < 64; ++n) {
        float cv[4], sv[4];
        #pragma unroll
        for (int ii = 0; ii < 4; ++ii) cv[ii] = Ct[i0+ii][n];
        #pragma unroll
        for (int pp = 0; pp < 4; ++pp) sv[pp] = Sp[n][p0+pp];
        #pragma unroll
        for (int ii = 0; ii < 4; ++ii)
            #pragma unroll
            for (int pp = 0; pp < 4; ++pp) acc[ii][pp] += cv[ii]*sv[pp];
    }

    #pragma unroll
    for (int ii = 0; ii < 4; ++ii) {
        const int i = i0+ii;
        const int l = l0 + i;
        const float e = __expf(a_cs[i]);
        const u16* xr = xconv  + (size_t)(b*SEQLEN + l) * CONVDIM + h*HEADDIM + p0;
        const u16* zr = zxbcdt + (size_t)(b*SEQLEN + l) * DPROJ   + h*HEADDIM + p0;
        u16* yp = ybuf + (size_t)(b*SEQLEN + l) * DINNER + h*HEADDIM + p0;
        ushort4 yv4 = *(const ushort4*)yp;
        ushort4 xv4 = *(const ushort4*)xr;
        ushort4 zv4 = *(const ushort4*)zr;
        float yv[4] = {bf2f(yv4.x), bf2f(yv4.y), bf2f(yv4.z), bf2f(yv4.w)};
        float xv[4] = {bf2f(xv4.x), bf2f(xv4.y), bf2f(xv4.z), bf2f(xv4.w)};
        float zv[4] = {bf2f(zv4.x), bf2f(zv4.y), bf2f(zv4.z), bf2f(zv4.w)};
        ushort4 o;
        u16* op = (u16*)&o;
        #pragma unroll
        for (int pp = 0; pp < 4; ++pp) {
            const float y = yv[pp] + e*acc[ii][pp] + xv[pp]*Dh;
            const float sz = zv[pp] / (1.f + __expf(-zv[pp]));
            op[pp] = f2bf(y * sz);
        }
        *(ushort4*)yp = o;
    }
}

// ---------------------------------------------------------------------------
// RMSNorm over 1024, in place (bf16)
// ---------------------------------------------------------------------------
__global__ __launch_bounds__(256) void rmsnorm_kernel(u16* __restrict__ y,
                                                      const float* __restrict__ w)
{
    __shared__ float red[4];
    const int row = blockIdx.x;
    const int tid = threadIdx.x;
    ushort4* yp = (ushort4*)(y + (size_t)row * DINNER);
    ushort4 v = yp[tid];
    float f0 = bf2f(v.x), f1 = bf2f(v.y), f2 = bf2f(v.z), f3 = bf2f(v.w);
    float ss = f0*f0 + f1*f1 + f2*f2 + f3*f3;
    #pragma unroll
    for (int o = 32; o > 0; o >>= 1) ss += __shfl_down(ss, o);
    if ((tid & 63) == 0) red[tid >> 6] = ss;
    __syncthreads();
    const float total = red[0] + red[1] + red[2] + red[3];
    const float scale = rsqrtf(total * (1.f/1024.f) + 1e-5f);
    const float4 wv = ((const float4*)w)[tid];
    ushort4 o;
    o.x = f2bf(f0 * scale * wv.x);
    o.y = f2bf(f1 * scale * wv.y);
    o.z = f2bf(f2 * scale * wv.z);
    o.w = f2bf(f3 * scale * wv.w);
    yp[tid] = o;
}

// ---------------------------------------------------------------------------
extern "C" void kernel_launch(void* const* d_in, const int* in_sizes, int n_in,
                              void* d_out, int out_size, void* d_ws, size_t ws_size,
                              hipStream_t stream)
{
    const float* u          = (const float*)d_in[0];
    const float* in_proj_w  = (const float*)d_in[1];
    const float* conv_w     = (const float*)d_in[2];
    const float* conv_b     = (const float*)d_in[3];
    const float* dt_bias    = (const float*)d_in[4];
    const float* A_log      = (const float*)d_in[5];
    const float* Dvec       = (const float*)d_in[6];
    const float* norm_w     = (const float*)d_in[7];
    const float* out_proj_w = (const float*)d_in[8];
    float* out = (float*)d_out;

    // workspace layout (~181 MB)
    float* dtb  = (float*)d_ws;                              // ROWS*NHEADS
    float* dAb  = dtb  + (size_t)ROWS*NHEADS;
    float* acs  = dAb  + (size_t)ROWS*NHEADS;                // B*NC*H*CHUNK
    float* asum = acs  + (size_t)BATCH*NCHUNK*NHEADS*CHUNK;  // B*H*NC
    u16* zxbcdt = (u16*)(asum + (size_t)BATCH*NHEADS*NCHUNK);
    u16* xconv  = zxbcdt + (size_t)ROWS*DPROJ;
    u16* ybuf   = xconv  + (size_t)ROWS*CONVDIM;
    u16* states = ybuf   + (size_t)ROWS*DINNER;              // B*NC*H*64*64 (33.6MB)
    u16* w2b    = states + (size_t)BATCH*NCHUNK*NHEADS*DSTATE*HEADDIM;  // 256*1024
    // overlay: u_bf + w1b live inside states (dead until ssd_phaseA)
    u16* u_bf   = states;                         // 16384*256
    u16* w1b    = states + (size_t)ROWS*DMODEL;   // 2304*256 (zero-padded rows)

    // converts
    cvt_bf16<<<(ROWS*DMODEL/4+255)/256, 256, 0, stream>>>(u, u_bf, ROWS*DMODEL/4, ROWS, 8);
    cvt_bf16<<<(NPAD1*DMODEL/4+255)/256, 256, 0, stream>>>(in_proj_w, w1b, NPAD1*DMODEL/4, DPROJ, 8);
    cvt_bf16<<<(DMODEL*DINNER/4+255)/256, 256, 0, stream>>>(out_proj_w, w2b, DMODEL*DINNER/4, DMODEL, 10);

    // GEMM1: zxbcdt[16384][2192] = u_bf @ w1b^T
    gemm_mfma<DMODEL, true><<<dim3(NPAD1/128, ROWS/128), 256, 0, stream>>>(u_bf, w1b, zxbcdt, DPROJ);

    conv_kernel<<<(ROWS*CONVDIM)/256, 256, 0, stream>>>(zxbcdt, conv_w, conv_b, xconv);
    dt_kernel<<<(ROWS*NHEADS)/256, 256, 0, stream>>>(zxbcdt, dt_bias, A_log, dtb, dAb);
    ssd_phaseA<<<dim3(NHEADS, NCHUNK, BATCH), 256, 0, stream>>>(xconv, dtb, dAb, ybuf, states, acs, asum);
    ssd_scan<<<BATCH*NHEADS*16, 256, 0, stream>>>(states, asum);
    ssd_phaseC<<<dim3(NHEADS, NCHUNK, BATCH), 256, 0, stream>>>(xconv, zxbcdt, states, acs, Dvec, ybuf);
    rmsnorm_kernel<<<ROWS, 256, 0, stream>>>(ybuf, norm_w);

    // GEMM2: out[16384][256] = ybuf @ w2b^T
    gemm_mfma<DINNER, false><<<dim3(DMODEL/128, ROWS/128), 256, 0, stream>>>(ybuf, w2b, out, DMODEL);
}

// Round 7
// 424.021 us; speedup vs baseline: 1.7720x; 1.2603x over previous
//
#include <hip/hip_runtime.h>
#include <math.h>

#define BATCH   4
#define SEQLEN  4096
#define DMODEL  256
#define DINNER  1024
#define NHEADS  16
#define HEADDIM 64
#define DSTATE  64
#define CONVDIM 1152
#define DPROJ   2192
#define NCHUNK  64
#define CHUNK   64
#define ROWS    (BATCH*SEQLEN)   // 16384
#define NPAD1   2304             // DPROJ padded to multiple of 128
#define TS      72               // padded LDS row stride (u16) for 64-wide tiles

typedef unsigned short u16;
using frag  = __attribute__((ext_vector_type(8))) short;   // 8 bf16 (4 VGPRs)
using f32x4 = __attribute__((ext_vector_type(4))) float;

// bf16 <-> f32 helpers (storage-only precision loss, RNE rounding)
static __device__ __forceinline__ float bf2f(u16 u) {
    return __uint_as_float(((unsigned int)u) << 16);
}
static __device__ __forceinline__ u16 f2bf(float f) {
    unsigned int x = __float_as_uint(f);
    x += 0x7fffu + ((x >> 16) & 1u);
    return (u16)(x >> 16);
}

// ---------------------------------------------------------------------------
// fp32 -> bf16 convert (4 elems/thread). Rows >= valid_rows write zeros
// ---------------------------------------------------------------------------
__global__ __launch_bounds__(256) void cvt_bf16(const float* __restrict__ in,
                                                u16* __restrict__ out,
                                                int total4, int valid_rows, int colshift)
{
    const int i = blockIdx.x * 256 + threadIdx.x;
    if (i >= total4) return;
    const int e = i * 4;
    const int row = e >> colshift;
    ushort4 o;
    if (row < valid_rows) {
        float4 v = *(const float4*)(in + e);
        o.x = f2bf(v.x); o.y = f2bf(v.y); o.z = f2bf(v.z); o.w = f2bf(v.w);
    } else {
        o.x = 0; o.y = 0; o.z = 0; o.w = 0;
    }
    *(ushort4*)(out + e) = o;
}

// ---------------------------------------------------------------------------
// bf16 MFMA GEMM: C[M][N] = A[M][KTOT] @ W[N][KTOT]^T   (unchanged from r4)
// ---------------------------------------------------------------------------
template<int KTOT, bool C_BF>
__global__ __launch_bounds__(256) void gemm_mfma(const u16* __restrict__ A,
                                                 const u16* __restrict__ W,
                                                 void* __restrict__ Cp,
                                                 int N)
{
    __shared__ u16 As[128*64];
    __shared__ u16 Ws[128*64];

    const int m0 = blockIdx.y * 128;
    const int n0 = blockIdx.x * 128;
    const int tid = threadIdx.x;
    const int lane = tid & 63;
    const int w  = tid >> 6;
    const int wr = w >> 1, wc = w & 1;

    const int srow = tid >> 3;          // 0..31
    const int scol = (tid & 7) * 8;     // 0..56

    const int lrow = lane & 15;
    const int kgrp = lane >> 4;         // 0..3

    f32x4 acc[4][4] = {};

    uint4 ra[4], rw[4];
    #pragma unroll
    for (int it = 0; it < 4; ++it) {
        const int r = it*32 + srow;
        ra[it] = *(const uint4*)(A + (size_t)(m0 + r)*KTOT + scol);
        rw[it] = *(const uint4*)(W + (size_t)(n0 + r)*KTOT + scol);
    }

    for (int kt = 0; kt < KTOT; kt += 64) {
        __syncthreads();
        #pragma unroll
        for (int it = 0; it < 4; ++it) {
            const int r = it*32 + srow;
            *(uint4*)&As[r*64 + scol] = ra[it];
            *(uint4*)&Ws[r*64 + scol] = rw[it];
        }
        __syncthreads();
        if (kt + 64 < KTOT) {
            #pragma unroll
            for (int it = 0; it < 4; ++it) {
                const int r = it*32 + srow;
                ra[it] = *(const uint4*)(A + (size_t)(m0 + r)*KTOT + kt + 64 + scol);
                rw[it] = *(const uint4*)(W + (size_t)(n0 + r)*KTOT + kt + 64 + scol);
            }
        }
        #pragma unroll
        for (int ks = 0; ks < 2; ++ks) {
            frag af[4], bf[4];
            #pragma unroll
            for (int i = 0; i < 4; ++i)
                af[i] = *(const frag*)&As[(wr*64 + i*16 + lrow)*64 + ks*32 + kgrp*8];
            #pragma unroll
            for (int j = 0; j < 4; ++j)
                bf[j] = *(const frag*)&Ws[(wc*64 + j*16 + lrow)*64 + ks*32 + kgrp*8];
            #pragma unroll
            for (int i = 0; i < 4; ++i)
                #pragma unroll
                for (int j = 0; j < 4; ++j)
                    acc[i][j] = __builtin_amdgcn_mfma_f32_16x16x32_bf16(af[i], bf[j], acc[i][j], 0, 0, 0);
        }
    }

    #pragma unroll
    for (int i = 0; i < 4; ++i) {
        #pragma unroll
        for (int j = 0; j < 4; ++j) {
            const int col = n0 + wc*64 + j*16 + lrow;
            if (col < N) {
                #pragma unroll
                for (int r = 0; r < 4; ++r) {
                    const int row = m0 + wr*64 + i*16 + kgrp*4 + r;
                    if constexpr (C_BF)
                        ((u16*)Cp)[(size_t)row * N + col] = f2bf(acc[i][j][r]);
                    else
                        ((float*)Cp)[(size_t)row * N + col] = acc[i][j][r];
                }
            }
        }
    }
}

// ---------------------------------------------------------------------------
// Depthwise causal conv (W=4) + bias + SiLU
// ---------------------------------------------------------------------------
__global__ __launch_bounds__(256) void conv_kernel(const u16* __restrict__ zxbcdt,
                                                   const float* __restrict__ conv_w,
                                                   const float* __restrict__ conv_b,
                                                   u16* __restrict__ xconv)
{
    const int idx = blockIdx.x * 256 + threadIdx.x;
    const int ch  = idx % CONVDIM;
    const int row = idx / CONVDIM;
    const int l   = row & (SEQLEN-1);
    const int b   = row >> 12;

    float acc = conv_b[ch];
    #pragma unroll
    for (int w = 0; w < 4; ++w) {
        const int ls = l - 3 + w;
        if (ls >= 0) {
            acc += bf2f(zxbcdt[(size_t)(b*SEQLEN + ls) * DPROJ + DINNER + ch]) * conv_w[ch*4 + w];
        }
    }
    xconv[idx] = f2bf(acc / (1.f + __expf(-acc)));
}

// ---------------------------------------------------------------------------
// dt = softplus(raw + dt_bias);  dA = -exp(A_log) * dt
// ---------------------------------------------------------------------------
__global__ __launch_bounds__(256) void dt_kernel(const u16* __restrict__ zxbcdt,
                                                 const float* __restrict__ dt_bias,
                                                 const float* __restrict__ A_log,
                                                 float* __restrict__ dt,
                                                 float* __restrict__ dA)
{
    const int idx = blockIdx.x * 256 + threadIdx.x;
    const int h = idx & (NHEADS-1);
    const int row = idx >> 4;
    const float x = bf2f(zxbcdt[(size_t)row * DPROJ + (DPROJ - NHEADS) + h]) + dt_bias[h];
    const float sp = (x > 20.f) ? x : log1pf(__expf(x));
    dt[idx] = sp;
    dA[idx] = -__expf(A_log[h]) * sp;
}

// ---------------------------------------------------------------------------
// SSD phase A (MFMA): per (b, chunk, head):
//   G = C @ B^T ; M = tril(G)*exp(acs_i - acs_j)    (in-register mask)
//   Y_diag = M @ xdt          -> ybuf
//   S^T    = xdt^T @ Bscaled  -> statesT [p][n]
// Tiles: C/M [i|j][n|j] row-major (stride TS); xdtT[p][j], BtT[n][j]
// transposed at stage, columns XOR-swizzled by (row&0x38) (8-block granular).
// Single __syncthreads(): each wave only reads its own M rows afterwards.
// ---------------------------------------------------------------------------
__global__ __launch_bounds__(256) void ssd_phaseA(const u16* __restrict__ xconv,
                                                  const float* __restrict__ dtb,
                                                  const float* __restrict__ dAb,
                                                  u16* __restrict__ ybuf,
                                                  u16* __restrict__ statesT,
                                                  float* __restrict__ acs_g,
                                                  float* __restrict__ asum_g)
{
    const int h = blockIdx.x, c = blockIdx.y, b = blockIdx.z;
    const int tid = threadIdx.x;
    const int lane = tid & 63;
    const int w = tid >> 6;
    const int l0 = c * CHUNK;

    __shared__ u16 CtM[64*TS];   // C tile, then overwritten (own rows) by M
    __shared__ u16 Bt [64*TS];   // B row-major [j][n]
    __shared__ u16 BtT[64*TS];   // decay-scaled B^T [n][j^swz]
    __shared__ u16 xdtT[64*TS];  // (x*dt)^T [p][j^swz]
    __shared__ float a_cs[64];

    // inclusive cumsum of dA over the chunk (wave 0, shfl scan)
    if (w == 0) {
        float v = dAb[(size_t)(b*SEQLEN + l0 + lane)*NHEADS + h];
        #pragma unroll
        for (int o = 1; o < 64; o <<= 1) {
            float t = __shfl_up(v, o, 64);
            if (lane >= o) v += t;
        }
        a_cs[lane] = v;
    }
    __syncthreads();
    const float a_last = a_cs[63];

    // staging: thread t -> row j = t>>2, 16-col block q0 = (t&3)*16
    {
        const int j  = tid >> 2;
        const int q0 = (tid & 3) * 16;
        const u16* rp = xconv + (size_t)(b*SEQLEN + l0 + j) * CONVDIM;
        const float dtv = dtb[(size_t)(b*SEQLEN + l0 + j)*NHEADS + h];
        const float dec = __expf(a_last - a_cs[j]);

        // C row-major (vectorized)
        *(uint4*)&CtM[j*TS + q0]     = *(const uint4*)(rp + DINNER + DSTATE + q0);
        *(uint4*)&CtM[j*TS + q0 + 8] = *(const uint4*)(rp + DINNER + DSTATE + q0 + 8);

        // B row-major + scaled transpose
        uint4 b0 = *(const uint4*)(rp + DINNER + q0);
        uint4 b1 = *(const uint4*)(rp + DINNER + q0 + 8);
        *(uint4*)&Bt[j*TS + q0]     = b0;
        *(uint4*)&Bt[j*TS + q0 + 8] = b1;
        unsigned int bw[8] = {b0.x, b0.y, b0.z, b0.w, b1.x, b1.y, b1.z, b1.w};
        #pragma unroll
        for (int s = 0; s < 8; ++s) {
            const int n0 = q0 + 2*s, n1 = n0 + 1;
            BtT[n0*TS + (j ^ (n0 & 0x38))] = f2bf(bf2f((u16)(bw[s] & 0xffff)) * dec);
            BtT[n1*TS + (j ^ (n1 & 0x38))] = f2bf(bf2f((u16)(bw[s] >> 16))    * dec);
        }

        // xdt transpose
        uint4 x0 = *(const uint4*)(rp + h*HEADDIM + q0);
        uint4 x1 = *(const uint4*)(rp + h*HEADDIM + q0 + 8);
        unsigned int xw[8] = {x0.x, x0.y, x0.z, x0.w, x1.x, x1.y, x1.z, x1.w};
        #pragma unroll
        for (int s = 0; s < 8; ++s) {
            const int p0 = q0 + 2*s, p1 = p0 + 1;
            xdtT[p0*TS + (j ^ (p0 & 0x38))] = f2bf(bf2f((u16)(xw[s] & 0xffff)) * dtv);
            xdtT[p1*TS + (j ^ (p1 & 0x38))] = f2bf(bf2f((u16)(xw[s] >> 16))    * dtv);
        }
    }
    __syncthreads();

    const int lrow = lane & 15;
    const int kgrp = lane >> 4;

    // ---- G = C @ B^T  (wave w owns output rows w*16..w*16+15) ----
    f32x4 accG[4] = {};
    #pragma unroll
    for (int ks = 0; ks < 2; ++ks) {
        frag a = *(const frag*)&CtM[(w*16 + lrow)*TS + ks*32 + kgrp*8];
        #pragma unroll
        for (int cf = 0; cf < 4; ++cf) {
            frag bb = *(const frag*)&Bt[(cf*16 + lrow)*TS + ks*32 + kgrp*8];
            accG[cf] = __builtin_amdgcn_mfma_f32_16x16x32_bf16(a, bb, accG[cf], 0, 0, 0);
        }
    }

    // ---- mask + decay, write M over own C rows (bf16) ----
    {
        float aj[4];
        #pragma unroll
        for (int cf = 0; cf < 4; ++cf) aj[cf] = a_cs[cf*16 + lrow];
        #pragma unroll
        for (int r = 0; r < 4; ++r) {
            const int i = w*16 + kgrp*4 + r;
            const float ai = a_cs[i];
            #pragma unroll
            for (int cf = 0; cf < 4; ++cf) {
                const int jcol = cf*16 + lrow;
                const float g = (jcol <= i) ? accG[cf][r] * __expf(ai - aj[cf]) : 0.f;
                CtM[i*TS + jcol] = f2bf(g);
            }
        }
    }

    // ---- Y_diag = M @ xdt  (A = own M rows, B = xdtT) ----
    f32x4 accY[4] = {};
    #pragma unroll
    for (int ks = 0; ks < 2; ++ks) {
        frag a = *(const frag*)&CtM[(w*16 + lrow)*TS + ks*32 + kgrp*8];
        #pragma unroll
        for (int cf = 0; cf < 4; ++cf) {
            const int p = cf*16 + lrow;
            frag bb = *(const frag*)&xdtT[p*TS + ((ks*32 + kgrp*8) ^ (p & 0x38))];
            accY[cf] = __builtin_amdgcn_mfma_f32_16x16x32_bf16(a, bb, accY[cf], 0, 0, 0);
        }
    }
    #pragma unroll
    for (int r = 0; r < 4; ++r) {
        const int i = w*16 + kgrp*4 + r;
        u16* yp = ybuf + (size_t)(b*SEQLEN + l0 + i)*DINNER + h*HEADDIM;
        #pragma unroll
        for (int cf = 0; cf < 4; ++cf)
            yp[cf*16 + lrow] = f2bf(accY[cf][r]);
    }

    // ---- S^T[p][n] = xdt^T @ Bscaled  (A = xdtT own rows, B = BtT) ----
    f32x4 accS[4] = {};
    #pragma unroll
    for (int ks = 0; ks < 2; ++ks) {
        const int pr = w*16 + lrow;
        frag a = *(const frag*)&xdtT[pr*TS + ((ks*32 + kgrp*8) ^ (pr & 0x38))];
        #pragma unroll
        for (int cf = 0; cf < 4; ++cf) {
            const int n = cf*16 + lrow;
            frag bb = *(const frag*)&BtT[n*TS + ((ks*32 + kgrp*8) ^ (n & 0x38))];
            accS[cf] = __builtin_amdgcn_mfma_f32_16x16x32_bf16(a, bb, accS[cf], 0, 0, 0);
        }
    }
    {
        u16* sp = statesT + (((size_t)b*NCHUNK + c)*NHEADS + h)*4096;
        #pragma unroll
        for (int r = 0; r < 4; ++r) {
            const int p = w*16 + kgrp*4 + r;
            #pragma unroll
            for (int cf = 0; cf < 4; ++cf)
                sp[p*64 + cf*16 + lrow] = f2bf(accS[cf][r]);
        }
    }

    if (tid < 64) acs_g[(((size_t)b*NCHUNK + c)*NHEADS + h)*CHUNK + tid] = a_cs[tid];
    if (tid == 0) asum_g[((size_t)b*NHEADS + h)*NCHUNK + c] = a_last;
}

// ---------------------------------------------------------------------------
// Inter-chunk scan, in place over statesT ([p][n] layout, elementwise)
// ---------------------------------------------------------------------------
__global__ __launch_bounds__(256) void ssd_scan(u16* __restrict__ statesT,
                                                const float* __restrict__ asum_g)
{
    const int gid = blockIdx.x;
    const int s = gid & 15;
    const int h = (gid >> 4) & (NHEADS-1);
    const int b = gid >> 8;
    const int elem = s*256 + threadIdx.x;

    const float* as = asum_g + ((size_t)b*NHEADS + h)*NCHUNK;
    float P = 0.f;
    for (int c = 0; c < NCHUNK; ++c) {
        const size_t idx = (((size_t)b*NCHUNK + c)*NHEADS + h)*4096 + elem;
        const float sv = bf2f(statesT[idx]);
        statesT[idx] = f2bf(P);
        P = P * __expf(as[c]) + sv;
    }
}

// ---------------------------------------------------------------------------
// SSD phase C (MFMA): Y = Y_diag + exp(a_cs)*(C @ Sp) + x*D ; y *= silu(z)
// statesT is [p][n] so B-operand (rows p, k=n) reads it directly.
// ---------------------------------------------------------------------------
__global__ __launch_bounds__(256) void ssd_phaseC(const u16* __restrict__ xconv,
                                                  const u16* __restrict__ zxbcdt,
                                                  const u16* __restrict__ statesT,
                                                  const float* __restrict__ acs_g,
                                                  const float* __restrict__ Dvec,
                                                  u16* __restrict__ ybuf)
{
    const int h = blockIdx.x, c = blockIdx.y, b = blockIdx.z;
    const int tid = threadIdx.x;
    const int lane = tid & 63;
    const int w = tid >> 6;
    const int l0 = c * CHUNK;

    __shared__ u16 Ct [64*TS];
    __shared__ u16 SpT[64*TS];
    __shared__ float a_cs[64];

    if (tid < 64) a_cs[tid] = acs_g[(((size_t)b*NCHUNK + c)*NHEADS + h)*CHUNK + tid];
    {
        const int r  = tid >> 2;
        const int q0 = (tid & 3) * 16;
        const u16* cp = xconv + (size_t)(b*SEQLEN + l0 + r)*CONVDIM + DINNER + DSTATE;
        *(uint4*)&Ct[r*TS + q0]     = *(const uint4*)(cp + q0);
        *(uint4*)&Ct[r*TS + q0 + 8] = *(const uint4*)(cp + q0 + 8);
        const u16* spg = statesT + (((size_t)b*NCHUNK + c)*NHEADS + h)*4096 + r*64;
        *(uint4*)&SpT[r*TS + q0]     = *(const uint4*)(spg + q0);
        *(uint4*)&SpT[r*TS + q0 + 8] = *(const uint4*)(spg + q0 + 8);
    }
    __syncthreads();

    const int lrow = lane & 15;
    const int kgrp = lane >> 4;

    f32x4 acc[4] = {};
    #pragma unroll
    for (int ks = 0; ks < 2; ++ks) {
        frag a = *(const frag*)&Ct[(w*16 + lrow)*TS + ks*32 + kgrp*8];
        #pragma unroll
        for (int cf = 0; cf < 4; ++cf) {
            frag bb = *(const frag*)&SpT[(cf*16 + lrow)*TS + ks*32 + kgrp*8];
            acc[cf] = __builtin_amdgcn_mfma_f32_16x16x32_bf16(a, bb, acc[cf], 0, 0, 0);
        }
    }

    const float Dh = Dvec[h];
    #pragma unroll
    for (int r = 0; r < 4; ++r) {
        const int i = w*16 + kgrp*4 + r;
        const int l = l0 + i;
        const float e = __expf(a_cs[i]);
        const u16* xr = xconv  + (size_t)(b*SEQLEN + l)*CONVDIM + h*HEADDIM;
        const u16* zr = zxbcdt + (size_t)(b*SEQLEN + l)*DPROJ   + h*HEADDIM;
        u16* yp = ybuf + (size_t)(b*SEQLEN + l)*DINNER + h*HEADDIM;
        #pragma unroll
        for (int cf = 0; cf < 4; ++cf) {
            const int p = cf*16 + lrow;
            const float yv = bf2f(yp[p]) + e*acc[cf][r] + bf2f(xr[p])*Dh;
            const float zv = bf2f(zr[p]);
            yp[p] = f2bf(yv * (zv / (1.f + __expf(-zv))));
        }
    }
}

// ---------------------------------------------------------------------------
// RMSNorm over 1024, in place (bf16)
// ---------------------------------------------------------------------------
__global__ __launch_bounds__(256) void rmsnorm_kernel(u16* __restrict__ y,
                                                      const float* __restrict__ w)
{
    __shared__ float red[4];
    const int row = blockIdx.x;
    const int tid = threadIdx.x;
    ushort4* yp = (ushort4*)(y + (size_t)row * DINNER);
    ushort4 v = yp[tid];
    float f0 = bf2f(v.x), f1 = bf2f(v.y), f2 = bf2f(v.z), f3 = bf2f(v.w);
    float ss = f0*f0 + f1*f1 + f2*f2 + f3*f3;
    #pragma unroll
    for (int o = 32; o > 0; o >>= 1) ss += __shfl_down(ss, o);
    if ((tid & 63) == 0) red[tid >> 6] = ss;
    __syncthreads();
    const float total = red[0] + red[1] + red[2] + red[3];
    const float scale = rsqrtf(total * (1.f/1024.f) + 1e-5f);
    const float4 wv = ((const float4*)w)[tid];
    ushort4 o;
    o.x = f2bf(f0 * scale * wv.x);
    o.y = f2bf(f1 * scale * wv.y);
    o.z = f2bf(f2 * scale * wv.z);
    o.w = f2bf(f3 * scale * wv.w);
    yp[tid] = o;
}

// ---------------------------------------------------------------------------
extern "C" void kernel_launch(void* const* d_in, const int* in_sizes, int n_in,
                              void* d_out, int out_size, void* d_ws, size_t ws_size,
                              hipStream_t stream)
{
    const float* u          = (const float*)d_in[0];
    const float* in_proj_w  = (const float*)d_in[1];
    const float* conv_w     = (const float*)d_in[2];
    const float* conv_b     = (const float*)d_in[3];
    const float* dt_bias    = (const float*)d_in[4];
    const float* A_log      = (const float*)d_in[5];
    const float* Dvec       = (const float*)d_in[6];
    const float* norm_w     = (const float*)d_in[7];
    const float* out_proj_w = (const float*)d_in[8];
    float* out = (float*)d_out;

    // workspace layout (~181 MB)
    float* dtb  = (float*)d_ws;                              // ROWS*NHEADS
    float* dAb  = dtb  + (size_t)ROWS*NHEADS;
    float* acs  = dAb  + (size_t)ROWS*NHEADS;                // B*NC*H*CHUNK
    float* asum = acs  + (size_t)BATCH*NCHUNK*NHEADS*CHUNK;  // B*H*NC
    u16* zxbcdt = (u16*)(asum + (size_t)BATCH*NHEADS*NCHUNK);
    u16* xconv  = zxbcdt + (size_t)ROWS*DPROJ;
    u16* ybuf   = xconv  + (size_t)ROWS*CONVDIM;
    u16* states = ybuf   + (size_t)ROWS*DINNER;              // B*NC*H*64*64 ([p][n])
    u16* w2b    = states + (size_t)BATCH*NCHUNK*NHEADS*DSTATE*HEADDIM;
    // overlay: u_bf + w1b live inside states (dead until ssd_phaseA)
    u16* u_bf   = states;                         // 16384*256
    u16* w1b    = states + (size_t)ROWS*DMODEL;   // 2304*256 (zero-padded rows)

    cvt_bf16<<<(ROWS*DMODEL/4+255)/256, 256, 0, stream>>>(u, u_bf, ROWS*DMODEL/4, ROWS, 8);
    cvt_bf16<<<(NPAD1*DMODEL/4+255)/256, 256, 0, stream>>>(in_proj_w, w1b, NPAD1*DMODEL/4, DPROJ, 8);
    cvt_bf16<<<(DMODEL*DINNER/4+255)/256, 256, 0, stream>>>(out_proj_w, w2b, DMODEL*DINNER/4, DMODEL, 10);

    gemm_mfma<DMODEL, true><<<dim3(NPAD1/128, ROWS/128), 256, 0, stream>>>(u_bf, w1b, zxbcdt, DPROJ);

    conv_kernel<<<(ROWS*CONVDIM)/256, 256, 0, stream>>>(zxbcdt, conv_w, conv_b, xconv);
    dt_kernel<<<(ROWS*NHEADS)/256, 256, 0, stream>>>(zxbcdt, dt_bias, A_log, dtb, dAb);
    ssd_phaseA<<<dim3(NHEADS, NCHUNK, BATCH), 256, 0, stream>>>(xconv, dtb, dAb, ybuf, states, acs, asum);
    ssd_scan<<<BATCH*NHEADS*16, 256, 0, stream>>>(states, asum);
    ssd_phaseC<<<dim3(NHEADS, NCHUNK, BATCH), 256, 0, stream>>>(xconv, zxbcdt, states, acs, Dvec, ybuf);
    rmsnorm_kernel<<<ROWS, 256, 0, stream>>>(ybuf, norm_w);

    gemm_mfma<DINNER, false><<<dim3(DMODEL/128, ROWS/128), 256, 0, stream>>>(ybuf, w2b, out, DMODEL);
}

// Round 8
// 420.708 us; speedup vs baseline: 1.7860x; 1.0079x over previous
//
#include <hip/hip_runtime.h>
#include <math.h>

#define BATCH   4
#define SEQLEN  4096
#define DMODEL  256
#define DINNER  1024
#define NHEADS  16
#define HEADDIM 64
#define DSTATE  64
#define CONVDIM 1152
#define DPROJ   2192
#define NCHUNK  64
#define CHUNK   64
#define ROWS    (BATCH*SEQLEN)   // 16384
#define NPAD1   2304             // DPROJ padded to multiple of 128
#define TS      72               // padded LDS row stride (u16) for 64-wide tiles

typedef unsigned short u16;
using frag  = __attribute__((ext_vector_type(8))) short;   // 8 bf16 (4 VGPRs)
using f32x4 = __attribute__((ext_vector_type(4))) float;

// bf16 <-> f32 helpers (storage-only precision loss, RNE rounding)
static __device__ __forceinline__ float bf2f(u16 u) {
    return __uint_as_float(((unsigned int)u) << 16);
}
static __device__ __forceinline__ u16 f2bf(float f) {
    unsigned int x = __float_as_uint(f);
    x += 0x7fffu + ((x >> 16) & 1u);
    return (u16)(x >> 16);
}

// ---------------------------------------------------------------------------
// fp32 -> bf16 convert (4 elems/thread). Rows >= valid_rows write zeros
// ---------------------------------------------------------------------------
__global__ __launch_bounds__(256) void cvt_bf16(const float* __restrict__ in,
                                                u16* __restrict__ out,
                                                int total4, int valid_rows, int colshift)
{
    const int i = blockIdx.x * 256 + threadIdx.x;
    if (i >= total4) return;
    const int e = i * 4;
    const int row = e >> colshift;
    ushort4 o;
    if (row < valid_rows) {
        float4 v = *(const float4*)(in + e);
        o.x = f2bf(v.x); o.y = f2bf(v.y); o.z = f2bf(v.z); o.w = f2bf(v.w);
    } else {
        o.x = 0; o.y = 0; o.z = 0; o.w = 0;
    }
    *(ushort4*)(out + e) = o;
}

// ---------------------------------------------------------------------------
// bf16 MFMA GEMM: C[M][N] = A[M][KTOT] @ W[N][KTOT]^T
// 128x128 tile, BK=64, 256 threads = 4 waves (2x2 of 64x64 each).
// LDS k-slots XOR-swizzled by (row&7) to kill 16-way frag-read conflicts.
// bf16 epilogue staged through LDS -> coalesced dwordx4 stores (16B/lane).
// ---------------------------------------------------------------------------
template<int KTOT, bool C_BF>
__global__ __launch_bounds__(256) void gemm_mfma(const u16* __restrict__ A,
                                                 const u16* __restrict__ W,
                                                 void* __restrict__ Cp,
                                                 int N)
{
    __shared__ u16 pool[128*136];          // 34816 B; staging uses first 32 KB
    u16* As = pool;                        // [128][64] swizzled
    u16* Ws = pool + 128*64;               // [128][64] swizzled

    const int m0 = blockIdx.y * 128;
    const int n0 = blockIdx.x * 128;
    const int tid = threadIdx.x;
    const int lane = tid & 63;
    const int w  = tid >> 6;
    const int wr = w >> 1, wc = w & 1;

    const int srow = tid >> 3;             // 0..31
    const int scol = (tid & 7) * 8;        // 0..56
    const int ssw  = scol ^ ((srow & 7) * 8);   // swizzled stage slot

    const int lrow = lane & 15;
    const int kgrp = lane >> 4;            // 0..3
    const int swz  = (lrow & 7) * 8;       // frag-read slot XOR

    f32x4 acc[4][4] = {};

    uint4 ra[4], rw[4];
    #pragma unroll
    for (int it = 0; it < 4; ++it) {
        const int r = it*32 + srow;
        ra[it] = *(const uint4*)(A + (size_t)(m0 + r)*KTOT + scol);
        rw[it] = *(const uint4*)(W + (size_t)(n0 + r)*KTOT + scol);
    }

    for (int kt = 0; kt < KTOT; kt += 64) {
        __syncthreads();
        #pragma unroll
        for (int it = 0; it < 4; ++it) {
            const int r = it*32 + srow;
            *(uint4*)&As[r*64 + ssw] = ra[it];
            *(uint4*)&Ws[r*64 + ssw] = rw[it];
        }
        __syncthreads();
        if (kt + 64 < KTOT) {
            #pragma unroll
            for (int it = 0; it < 4; ++it) {
                const int r = it*32 + srow;
                ra[it] = *(const uint4*)(A + (size_t)(m0 + r)*KTOT + kt + 64 + scol);
                rw[it] = *(const uint4*)(W + (size_t)(n0 + r)*KTOT + kt + 64 + scol);
            }
        }
        #pragma unroll
        for (int ks = 0; ks < 2; ++ks) {
            const int kx = (ks*32 + kgrp*8) ^ swz;
            frag af[4], bf[4];
            #pragma unroll
            for (int i = 0; i < 4; ++i)
                af[i] = *(const frag*)&As[(wr*64 + i*16 + lrow)*64 + kx];
            #pragma unroll
            for (int j = 0; j < 4; ++j)
                bf[j] = *(const frag*)&Ws[(wc*64 + j*16 + lrow)*64 + kx];
            #pragma unroll
            for (int i = 0; i < 4; ++i)
                #pragma unroll
                for (int j = 0; j < 4; ++j)
                    acc[i][j] = __builtin_amdgcn_mfma_f32_16x16x32_bf16(af[i], bf[j], acc[i][j], 0, 0, 0);
        }
    }

    if constexpr (C_BF) {
        // stage accumulators to LDS (bf16, padded stride 136), then
        // fully-coalesced dwordx4 stores: 16B/lane, 4KB/instruction.
        __syncthreads();   // all frag reads done before pool overwrite
        #pragma unroll
        for (int i = 0; i < 4; ++i)
            #pragma unroll
            for (int j = 0; j < 4; ++j)
                #pragma unroll
                for (int r = 0; r < 4; ++r)
                    pool[(wr*64 + i*16 + kgrp*4 + r)*136 + wc*64 + j*16 + lrow] =
                        f2bf(acc[i][j][r]);
        __syncthreads();
        #pragma unroll
        for (int q = 0; q < 8; ++q) {
            const int f  = q*2048 + tid*8;
            const int rl = f >> 7;
            const int cl = f & 127;
            const int col = n0 + cl;
            if (col < N)   // col 8-aligned, N%8==0 -> whole vec4 in range
                *(uint4*)((u16*)Cp + (size_t)(m0 + rl)*N + col) =
                    *(const uint4*)&pool[rl*136 + cl];
        }
    } else {
        // fp32 path: 16 lanes x 4B = full 64B sectors already; keep direct.
        #pragma unroll
        for (int i = 0; i < 4; ++i) {
            #pragma unroll
            for (int j = 0; j < 4; ++j) {
                const int col = n0 + wc*64 + j*16 + lrow;
                if (col < N) {
                    #pragma unroll
                    for (int r = 0; r < 4; ++r) {
                        const int row = m0 + wr*64 + i*16 + kgrp*4 + r;
                        ((float*)Cp)[(size_t)row * N + col] = acc[i][j][r];
                    }
                }
            }
        }
    }
}

// ---------------------------------------------------------------------------
// Depthwise causal conv (W=4) + bias + SiLU
// ---------------------------------------------------------------------------
__global__ __launch_bounds__(256) void conv_kernel(const u16* __restrict__ zxbcdt,
                                                   const float* __restrict__ conv_w,
                                                   const float* __restrict__ conv_b,
                                                   u16* __restrict__ xconv)
{
    const int idx = blockIdx.x * 256 + threadIdx.x;
    const int ch  = idx % CONVDIM;
    const int row = idx / CONVDIM;
    const int l   = row & (SEQLEN-1);
    const int b   = row >> 12;

    float acc = conv_b[ch];
    #pragma unroll
    for (int w = 0; w < 4; ++w) {
        const int ls = l - 3 + w;
        if (ls >= 0) {
            acc += bf2f(zxbcdt[(size_t)(b*SEQLEN + ls) * DPROJ + DINNER + ch]) * conv_w[ch*4 + w];
        }
    }
    xconv[idx] = f2bf(acc / (1.f + __expf(-acc)));
}

// ---------------------------------------------------------------------------
// dt = softplus(raw + dt_bias);  dA = -exp(A_log) * dt
// ---------------------------------------------------------------------------
__global__ __launch_bounds__(256) void dt_kernel(const u16* __restrict__ zxbcdt,
                                                 const float* __restrict__ dt_bias,
                                                 const float* __restrict__ A_log,
                                                 float* __restrict__ dt,
                                                 float* __restrict__ dA)
{
    const int idx = blockIdx.x * 256 + threadIdx.x;
    const int h = idx & (NHEADS-1);
    const int row = idx >> 4;
    const float x = bf2f(zxbcdt[(size_t)row * DPROJ + (DPROJ - NHEADS) + h]) + dt_bias[h];
    const float sp = (x > 20.f) ? x : log1pf(__expf(x));
    dt[idx] = sp;
    dA[idx] = -__expf(A_log[h]) * sp;
}

// ---------------------------------------------------------------------------
// SSD phase A (MFMA): per (b, chunk, head):
//   G = C @ B^T ; M = tril(G)*exp(acs_i - acs_j)    (in-register mask)
//   Y_diag = M @ xdt          -> ybuf
//   S^T    = xdt^T @ Bscaled  -> statesT [p][n]
// ---------------------------------------------------------------------------
__global__ __launch_bounds__(256) void ssd_phaseA(const u16* __restrict__ xconv,
                                                  const float* __restrict__ dtb,
                                                  const float* __restrict__ dAb,
                                                  u16* __restrict__ ybuf,
                                                  u16* __restrict__ statesT,
                                                  float* __restrict__ acs_g,
                                                  float* __restrict__ asum_g)
{
    const int h = blockIdx.x, c = blockIdx.y, b = blockIdx.z;
    const int tid = threadIdx.x;
    const int lane = tid & 63;
    const int w = tid >> 6;
    const int l0 = c * CHUNK;

    __shared__ u16 CtM[64*TS];   // C tile, then overwritten (own rows) by M
    __shared__ u16 Bt [64*TS];   // B row-major [j][n]
    __shared__ u16 BtT[64*TS];   // decay-scaled B^T [n][j^swz]
    __shared__ u16 xdtT[64*TS];  // (x*dt)^T [p][j^swz]
    __shared__ float a_cs[64];

    // inclusive cumsum of dA over the chunk (wave 0, shfl scan)
    if (w == 0) {
        float v = dAb[(size_t)(b*SEQLEN + l0 + lane)*NHEADS + h];
        #pragma unroll
        for (int o = 1; o < 64; o <<= 1) {
            float t = __shfl_up(v, o, 64);
            if (lane >= o) v += t;
        }
        a_cs[lane] = v;
    }
    __syncthreads();
    const float a_last = a_cs[63];

    // staging: thread t -> row j = t>>2, 16-col block q0 = (t&3)*16
    {
        const int j  = tid >> 2;
        const int q0 = (tid & 3) * 16;
        const u16* rp = xconv + (size_t)(b*SEQLEN + l0 + j) * CONVDIM;
        const float dtv = dtb[(size_t)(b*SEQLEN + l0 + j)*NHEADS + h];
        const float dec = __expf(a_last - a_cs[j]);

        // C row-major (vectorized)
        *(uint4*)&CtM[j*TS + q0]     = *(const uint4*)(rp + DINNER + DSTATE + q0);
        *(uint4*)&CtM[j*TS + q0 + 8] = *(const uint4*)(rp + DINNER + DSTATE + q0 + 8);

        // B row-major + scaled transpose
        uint4 b0 = *(const uint4*)(rp + DINNER + q0);
        uint4 b1 = *(const uint4*)(rp + DINNER + q0 + 8);
        *(uint4*)&Bt[j*TS + q0]     = b0;
        *(uint4*)&Bt[j*TS + q0 + 8] = b1;
        unsigned int bw[8] = {b0.x, b0.y, b0.z, b0.w, b1.x, b1.y, b1.z, b1.w};
        #pragma unroll
        for (int s = 0; s < 8; ++s) {
            const int n0 = q0 + 2*s, n1 = n0 + 1;
            BtT[n0*TS + (j ^ (n0 & 0x38))] = f2bf(bf2f((u16)(bw[s] & 0xffff)) * dec);
            BtT[n1*TS + (j ^ (n1 & 0x38))] = f2bf(bf2f((u16)(bw[s] >> 16))    * dec);
        }

        // xdt transpose
        uint4 x0 = *(const uint4*)(rp + h*HEADDIM + q0);
        uint4 x1 = *(const uint4*)(rp + h*HEADDIM + q0 + 8);
        unsigned int xw[8] = {x0.x, x0.y, x0.z, x0.w, x1.x, x1.y, x1.z, x1.w};
        #pragma unroll
        for (int s = 0; s < 8; ++s) {
            const int p0 = q0 + 2*s, p1 = p0 + 1;
            xdtT[p0*TS + (j ^ (p0 & 0x38))] = f2bf(bf2f((u16)(xw[s] & 0xffff)) * dtv);
            xdtT[p1*TS + (j ^ (p1 & 0x38))] = f2bf(bf2f((u16)(xw[s] >> 16))    * dtv);
        }
    }
    __syncthreads();

    const int lrow = lane & 15;
    const int kgrp = lane >> 4;

    // ---- G = C @ B^T  (wave w owns output rows w*16..w*16+15) ----
    f32x4 accG[4] = {};
    #pragma unroll
    for (int ks = 0; ks < 2; ++ks) {
        frag a = *(const frag*)&CtM[(w*16 + lrow)*TS + ks*32 + kgrp*8];
        #pragma unroll
        for (int cf = 0; cf < 4; ++cf) {
            frag bb = *(const frag*)&Bt[(cf*16 + lrow)*TS + ks*32 + kgrp*8];
            accG[cf] = __builtin_amdgcn_mfma_f32_16x16x32_bf16(a, bb, accG[cf], 0, 0, 0);
        }
    }

    // ---- mask + decay, write M over own C rows (bf16) ----
    {
        float aj[4];
        #pragma unroll
        for (int cf = 0; cf < 4; ++cf) aj[cf] = a_cs[cf*16 + lrow];
        #pragma unroll
        for (int r = 0; r < 4; ++r) {
            const int i = w*16 + kgrp*4 + r;
            const float ai = a_cs[i];
            #pragma unroll
            for (int cf = 0; cf < 4; ++cf) {
                const int jcol = cf*16 + lrow;
                const float g = (jcol <= i) ? accG[cf][r] * __expf(ai - aj[cf]) : 0.f;
                CtM[i*TS + jcol] = f2bf(g);
            }
        }
    }

    // ---- Y_diag = M @ xdt  (A = own M rows, B = xdtT) ----
    f32x4 accY[4] = {};
    #pragma unroll
    for (int ks = 0; ks < 2; ++ks) {
        frag a = *(const frag*)&CtM[(w*16 + lrow)*TS + ks*32 + kgrp*8];
        #pragma unroll
        for (int cf = 0; cf < 4; ++cf) {
            const int p = cf*16 + lrow;
            frag bb = *(const frag*)&xdtT[p*TS + ((ks*32 + kgrp*8) ^ (p & 0x38))];
            accY[cf] = __builtin_amdgcn_mfma_f32_16x16x32_bf16(a, bb, accY[cf], 0, 0, 0);
        }
    }
    #pragma unroll
    for (int r = 0; r < 4; ++r) {
        const int i = w*16 + kgrp*4 + r;
        u16* yp = ybuf + (size_t)(b*SEQLEN + l0 + i)*DINNER + h*HEADDIM;
        #pragma unroll
        for (int cf = 0; cf < 4; ++cf)
            yp[cf*16 + lrow] = f2bf(accY[cf][r]);
    }

    // ---- S^T[p][n] = xdt^T @ Bscaled  (A = xdtT own rows, B = BtT) ----
    f32x4 accS[4] = {};
    #pragma unroll
    for (int ks = 0; ks < 2; ++ks) {
        const int pr = w*16 + lrow;
        frag a = *(const frag*)&xdtT[pr*TS + ((ks*32 + kgrp*8) ^ (pr & 0x38))];
        #pragma unroll
        for (int cf = 0; cf < 4; ++cf) {
            const int n = cf*16 + lrow;
            frag bb = *(const frag*)&BtT[n*TS + ((ks*32 + kgrp*8) ^ (n & 0x38))];
            accS[cf] = __builtin_amdgcn_mfma_f32_16x16x32_bf16(a, bb, accS[cf], 0, 0, 0);
        }
    }
    {
        u16* sp = statesT + (((size_t)b*NCHUNK + c)*NHEADS + h)*4096;
        #pragma unroll
        for (int r = 0; r < 4; ++r) {
            const int p = w*16 + kgrp*4 + r;
            #pragma unroll
            for (int cf = 0; cf < 4; ++cf)
                sp[p*64 + cf*16 + lrow] = f2bf(accS[cf][r]);
        }
    }

    if (tid < 64) acs_g[(((size_t)b*NCHUNK + c)*NHEADS + h)*CHUNK + tid] = a_cs[tid];
    if (tid == 0) asum_g[((size_t)b*NHEADS + h)*NCHUNK + c] = a_last;
}

// ---------------------------------------------------------------------------
// Inter-chunk scan, in place over statesT ([p][n] layout, elementwise)
// ---------------------------------------------------------------------------
__global__ __launch_bounds__(256) void ssd_scan(u16* __restrict__ statesT,
                                                const float* __restrict__ asum_g)
{
    const int gid = blockIdx.x;
    const int s = gid & 15;
    const int h = (gid >> 4) & (NHEADS-1);
    const int b = gid >> 8;
    const int elem = s*256 + threadIdx.x;

    const float* as = asum_g + ((size_t)b*NHEADS + h)*NCHUNK;
    float P = 0.f;
    for (int c = 0; c < NCHUNK; ++c) {
        const size_t idx = (((size_t)b*NCHUNK + c)*NHEADS + h)*4096 + elem;
        const float sv = bf2f(statesT[idx]);
        statesT[idx] = f2bf(P);
        P = P * __expf(as[c]) + sv;
    }
}

// ---------------------------------------------------------------------------
// SSD phase C (MFMA): Y = Y_diag + exp(a_cs)*(C @ Sp) + x*D ; y *= silu(z)
// ---------------------------------------------------------------------------
__global__ __launch_bounds__(256) void ssd_phaseC(const u16* __restrict__ xconv,
                                                  const u16* __restrict__ zxbcdt,
                                                  const u16* __restrict__ statesT,
                                                  const float* __restrict__ acs_g,
                                                  const float* __restrict__ Dvec,
                                                  u16* __restrict__ ybuf)
{
    const int h = blockIdx.x, c = blockIdx.y, b = blockIdx.z;
    const int tid = threadIdx.x;
    const int lane = tid & 63;
    const int w = tid >> 6;
    const int l0 = c * CHUNK;

    __shared__ u16 Ct [64*TS];
    __shared__ u16 SpT[64*TS];
    __shared__ float a_cs[64];

    if (tid < 64) a_cs[tid] = acs_g[(((size_t)b*NCHUNK + c)*NHEADS + h)*CHUNK + tid];
    {
        const int r  = tid >> 2;
        const int q0 = (tid & 3) * 16;
        const u16* cp = xconv + (size_t)(b*SEQLEN + l0 + r)*CONVDIM + DINNER + DSTATE;
        *(uint4*)&Ct[r*TS + q0]     = *(const uint4*)(cp + q0);
        *(uint4*)&Ct[r*TS + q0 + 8] = *(const uint4*)(cp + q0 + 8);
        const u16* spg = statesT + (((size_t)b*NCHUNK + c)*NHEADS + h)*4096 + r*64;
        *(uint4*)&SpT[r*TS + q0]     = *(const uint4*)(spg + q0);
        *(uint4*)&SpT[r*TS + q0 + 8] = *(const uint4*)(spg + q0 + 8);
    }
    __syncthreads();

    const int lrow = lane & 15;
    const int kgrp = lane >> 4;

    f32x4 acc[4] = {};
    #pragma unroll
    for (int ks = 0; ks < 2; ++ks) {
        frag a = *(const frag*)&Ct[(w*16 + lrow)*TS + ks*32 + kgrp*8];
        #pragma unroll
        for (int cf = 0; cf < 4; ++cf) {
            frag bb = *(const frag*)&SpT[(cf*16 + lrow)*TS + ks*32 + kgrp*8];
            acc[cf] = __builtin_amdgcn_mfma_f32_16x16x32_bf16(a, bb, acc[cf], 0, 0, 0);
        }
    }

    const float Dh = Dvec[h];
    #pragma unroll
    for (int r = 0; r < 4; ++r) {
        const int i = w*16 + kgrp*4 + r;
        const int l = l0 + i;
        const float e = __expf(a_cs[i]);
        const u16* xr = xconv  + (size_t)(b*SEQLEN + l)*CONVDIM + h*HEADDIM;
        const u16* zr = zxbcdt + (size_t)(b*SEQLEN + l)*DPROJ   + h*HEADDIM;
        u16* yp = ybuf + (size_t)(b*SEQLEN + l)*DINNER + h*HEADDIM;
        #pragma unroll
        for (int cf = 0; cf < 4; ++cf) {
            const int p = cf*16 + lrow;
            const float yv = bf2f(yp[p]) + e*acc[cf][r] + bf2f(xr[p])*Dh;
            const float zv = bf2f(zr[p]);
            yp[p] = f2bf(yv * (zv / (1.f + __expf(-zv))));
        }
    }
}

// ---------------------------------------------------------------------------
// RMSNorm over 1024, in place (bf16)
// ---------------------------------------------------------------------------
__global__ __launch_bounds__(256) void rmsnorm_kernel(u16* __restrict__ y,
                                                      const float* __restrict__ w)
{
    __shared__ float red[4];
    const int row = blockIdx.x;
    const int tid = threadIdx.x;
    ushort4* yp = (ushort4*)(y + (size_t)row * DINNER);
    ushort4 v = yp[tid];
    float f0 = bf2f(v.x), f1 = bf2f(v.y), f2 = bf2f(v.z), f3 = bf2f(v.w);
    float ss = f0*f0 + f1*f1 + f2*f2 + f3*f3;
    #pragma unroll
    for (int o = 32; o > 0; o >>= 1) ss += __shfl_down(ss, o);
    if ((tid & 63) == 0) red[tid >> 6] = ss;
    __syncthreads();
    const float total = red[0] + red[1] + red[2] + red[3];
    const float scale = rsqrtf(total * (1.f/1024.f) + 1e-5f);
    const float4 wv = ((const float4*)w)[tid];
    ushort4 o;
    o.x = f2bf(f0 * scale * wv.x);
    o.y = f2bf(f1 * scale * wv.y);
    o.z = f2bf(f2 * scale * wv.z);
    o.w = f2bf(f3 * scale * wv.w);
    yp[tid] = o;
}

// ---------------------------------------------------------------------------
extern "C" void kernel_launch(void* const* d_in, const int* in_sizes, int n_in,
                              void* d_out, int out_size, void* d_ws, size_t ws_size,
                              hipStream_t stream)
{
    const float* u          = (const float*)d_in[0];
    const float* in_proj_w  = (const float*)d_in[1];
    const float* conv_w     = (const float*)d_in[2];
    const float* conv_b     = (const float*)d_in[3];
    const float* dt_bias    = (const float*)d_in[4];
    const float* A_log      = (const float*)d_in[5];
    const float* Dvec       = (const float*)d_in[6];
    const float* norm_w     = (const float*)d_in[7];
    const float* out_proj_w = (const float*)d_in[8];
    float* out = (float*)d_out;

    // workspace layout (~181 MB)
    float* dtb  = (float*)d_ws;                              // ROWS*NHEADS
    float* dAb  = dtb  + (size_t)ROWS*NHEADS;
    float* acs  = dAb  + (size_t)ROWS*NHEADS;                // B*NC*H*CHUNK
    float* asum = acs  + (size_t)BATCH*NCHUNK*NHEADS*CHUNK;  // B*H*NC
    u16* zxbcdt = (u16*)(asum + (size_t)BATCH*NHEADS*NCHUNK);
    u16* xconv  = zxbcdt + (size_t)ROWS*DPROJ;
    u16* ybuf   = xconv  + (size_t)ROWS*CONVDIM;
    u16* states = ybuf   + (size_t)ROWS*DINNER;              // B*NC*H*64*64 ([p][n])
    u16* w2b    = states + (size_t)BATCH*NCHUNK*NHEADS*DSTATE*HEADDIM;
    // overlay: u_bf + w1b live inside states (dead until ssd_phaseA)
    u16* u_bf   = states;                         // 16384*256
    u16* w1b    = states + (size_t)ROWS*DMODEL;   // 2304*256 (zero-padded rows)

    cvt_bf16<<<(ROWS*DMODEL/4+255)/256, 256, 0, stream>>>(u, u_bf, ROWS*DMODEL/4, ROWS, 8);
    cvt_bf16<<<(NPAD1*DMODEL/4+255)/256, 256, 0, stream>>>(in_proj_w, w1b, NPAD1*DMODEL/4, DPROJ, 8);
    cvt_bf16<<<(DMODEL*DINNER/4+255)/256, 256, 0, stream>>>(out_proj_w, w2b, DMODEL*DINNER/4, DMODEL, 10);

    gemm_mfma<DMODEL, true><<<dim3(NPAD1/128, ROWS/128), 256, 0, stream>>>(u_bf, w1b, zxbcdt, DPROJ);

    conv_kernel<<<(ROWS*CONVDIM)/256, 256, 0, stream>>>(zxbcdt, conv_w, conv_b, xconv);
    dt_kernel<<<(ROWS*NHEADS)/256, 256, 0, stream>>>(zxbcdt, dt_bias, A_log, dtb, dAb);
    ssd_phaseA<<<dim3(NHEADS, NCHUNK, BATCH), 256, 0, stream>>>(xconv, dtb, dAb, ybuf, states, acs, asum);
    ssd_scan<<<BATCH*NHEADS*16, 256, 0, stream>>>(states, asum);
    ssd_phaseC<<<dim3(NHEADS, NCHUNK, BATCH), 256, 0, stream>>>(xconv, zxbcdt, states, acs, Dvec, ybuf);
    rmsnorm_kernel<<<ROWS, 256, 0, stream>>>(ybuf, norm_w);

    gemm_mfma<DINNER, false><<<dim3(DMODEL/128, ROWS/128), 256, 0, stream>>>(ybuf, w2b, out, DMODEL);
}